// Round 1
// baseline (1729.390 us; speedup 1.0000x reference)
//
#include <hip/hip_runtime.h>
#include <math.h>
#include <stdint.h>

#define TOKENS 8192
#define DMODEL 1024
#define DFF    4096
#define NEXP   8
#define NROWS  (TOKENS * 2)

typedef float          vf4 __attribute__((ext_vector_type(4)));
typedef unsigned short vu4 __attribute__((ext_vector_type(4)));
typedef short          vs8 __attribute__((ext_vector_type(8)));
typedef float          facc __attribute__((ext_vector_type(4)));

__device__ __forceinline__ unsigned short f2bf(float f) {
    union { float f; unsigned u; } v; v.f = f;
    return (unsigned short)((v.u + 0x7FFFu + ((v.u >> 16) & 1u)) >> 16);
}
__device__ __forceinline__ int imin(int a, int b) { return a < b ? a : b; }

__device__ __forceinline__ void gl2lds16(const void* g, void* l) {
    __builtin_amdgcn_global_load_lds(
        (const __attribute__((address_space(1))) unsigned int*)g,
        (__attribute__((address_space(3))) unsigned int*)l, 16, 0, 0);
}

// ---------------- x fp32 -> bf16 ----------------
__global__ void k_convert_x(const float* __restrict__ x, unsigned short* __restrict__ xbf) {
    int i = blockIdx.x * 256 + threadIdx.x;   // one float4 per thread
    vf4 v = ((const vf4*)x)[i];
    vu4 o;
    o[0] = f2bf(v[0]); o[1] = f2bf(v[1]); o[2] = f2bf(v[2]); o[3] = f2bf(v[3]);
    ((vu4*)xbf)[i] = o;
}

// ---------------- transpose + bf16 convert: src[e][R][C] f32 -> dst[e][C][R] bf16 ----------------
__global__ void k_transpose_bf(const float* __restrict__ src, unsigned short* __restrict__ dst,
                               int R, int C) {
    __shared__ float tile[64][65];
    const int e = blockIdx.z;
    const float* s = src + (size_t)e * R * C;
    unsigned short* d = dst + (size_t)e * R * C;
    const int r0 = blockIdx.y * 64, c0 = blockIdx.x * 64;
    const int tr = threadIdx.x >> 4;          // 0..15
    const int tc = (threadIdx.x & 15) * 4;    // 0..60
    #pragma unroll
    for (int p = 0; p < 4; ++p) {
        int r = p * 16 + tr;
        vf4 v = *(const vf4*)(s + (size_t)(r0 + r) * C + c0 + tc);
        tile[r][tc + 0] = v[0]; tile[r][tc + 1] = v[1];
        tile[r][tc + 2] = v[2]; tile[r][tc + 3] = v[3];
    }
    __syncthreads();
    #pragma unroll
    for (int p = 0; p < 4; ++p) {
        int cc = p * 16 + tr;                 // transposed row index (c-dim)
        vu4 o;
        o[0] = f2bf(tile[tc + 0][cc]); o[1] = f2bf(tile[tc + 1][cc]);
        o[2] = f2bf(tile[tc + 2][cc]); o[3] = f2bf(tile[tc + 3][cc]);
        *(vu4*)(d + (size_t)(c0 + cc) * R + r0 + tc) = o;
    }
}

// ---------------- gate: logits -> softmax -> top2 -> weights, counts, prob sums ----------------
__global__ void k_gate(const float* __restrict__ x, const float* __restrict__ Wg,
                       int* __restrict__ counts, float* __restrict__ probsum,
                       int* __restrict__ tk_e, float* __restrict__ tk_w) {
    const int t = blockIdx.x;
    const int lane = threadIdx.x;             // 64 threads = 1 wave
    float acc[NEXP] = {0.f, 0.f, 0.f, 0.f, 0.f, 0.f, 0.f, 0.f};
    const float* xr = x + (size_t)t * DMODEL;
    #pragma unroll
    for (int i = 0; i < 16; ++i) {
        int dd = i * 64 + lane;
        float xv = xr[dd];
        const vf4* w = (const vf4*)(Wg + (size_t)dd * NEXP);
        vf4 a = w[0], b = w[1];
        acc[0] += xv * a[0]; acc[1] += xv * a[1]; acc[2] += xv * a[2]; acc[3] += xv * a[3];
        acc[4] += xv * b[0]; acc[5] += xv * b[1]; acc[6] += xv * b[2]; acc[7] += xv * b[3];
    }
    #pragma unroll
    for (int e = 0; e < NEXP; ++e) {
        float v = acc[e];
        for (int off = 32; off; off >>= 1) v += __shfl_xor(v, off, 64);
        acc[e] = v;
    }
    if (lane == 0) {
        float mx = acc[0];
        #pragma unroll
        for (int e = 1; e < NEXP; ++e) mx = fmaxf(mx, acc[e]);
        float p[NEXP], s = 0.f;
        #pragma unroll
        for (int e = 0; e < NEXP; ++e) { p[e] = expf(acc[e] - mx); s += p[e]; }
        float inv = 1.f / s;
        #pragma unroll
        for (int e = 0; e < NEXP; ++e) { p[e] *= inv; atomicAdd(&probsum[e], p[e]); }
        int i0 = 0; float b0 = p[0];
        #pragma unroll
        for (int e = 1; e < NEXP; ++e) if (p[e] > b0) { b0 = p[e]; i0 = e; }
        int i1 = -1; float b1 = -1.f;
        #pragma unroll
        for (int e = 0; e < NEXP; ++e) if (e != i0 && p[e] > b1) { b1 = p[e]; i1 = e; }
        float sn = 1.f / (b0 + b1 + 1e-8f);
        tk_e[t * 2 + 0] = i0; tk_w[t * 2 + 0] = b0 * sn;
        tk_e[t * 2 + 1] = i1; tk_w[t * 2 + 1] = b1 * sn;
        atomicAdd(&counts[i0], 1);
        atomicAdd(&counts[i1], 1);
    }
}

// ---------------- prefix bases + load-balance loss ----------------
__global__ void k_finalize(const int* __restrict__ counts, const float* __restrict__ probsum,
                           int* __restrict__ bases, float* __restrict__ out_loss) {
    if (threadIdx.x == 0) {
        int b = 0; float loss = 0.f;
        for (int e = 0; e < NEXP; ++e) {
            bases[e] = b; b += counts[e];
            loss += (probsum[e] / (float)TOKENS) * ((float)counts[e] / (float)NROWS);
        }
        out_loss[0] = (float)NEXP * loss;
    }
}

// ---------------- compact (token,slot) -> per-expert row lists ----------------
__global__ void k_build(const int* __restrict__ tk_e, const float* __restrict__ tk_w,
                        const int* __restrict__ bases, int* __restrict__ cursors,
                        int* __restrict__ row_token, float* __restrict__ row_weight) {
    int i = blockIdx.x * 256 + threadIdx.x;   // 0..16383
    int e = tk_e[i];
    int pos = atomicAdd(&cursors[e], 1);
    int row = bases[e] + pos;
    row_token[row] = i >> 1;
    row_weight[row] = tk_w[i];
}

// ---------------- pass A: H = gelu(X_gathered @ W1[e]), grouped 128x128 ----------------
__global__ __launch_bounds__(256) void k_ffn1(
    const unsigned short* __restrict__ xbf, const unsigned short* __restrict__ w1t,
    const int* __restrict__ counts, const int* __restrict__ bases,
    const int* __restrict__ row_token, unsigned short* __restrict__ h) {
    __shared__ unsigned short As[128 * 32];
    __shared__ unsigned short Bs[128 * 32];
    const int e = blockIdx.z;
    const int cnt = counts[e];
    const int m0 = blockIdx.y * 128;
    if (m0 >= cnt) return;
    const int n0 = blockIdx.x * 128;
    const int rb = bases[e];
    const int tid = threadIdx.x;
    const int wave = tid >> 6, lane = tid & 63;

    // staging: 512 16B-chunks per operand tile; slot s -> row s>>2, part s&3
    const int rA0 = tid >> 2,        pA0 = tid & 3;
    const int rA1 = (256 + tid) >> 2, pA1 = tid & 3;   // (256+tid)&3 == tid&3
    const int t0 = row_token[rb + imin(m0 + rA0, cnt - 1)];
    const int t1 = row_token[rb + imin(m0 + rA1, cnt - 1)];
    const unsigned short* gA0 = xbf + (size_t)t0 * DMODEL + pA0 * 8;
    const unsigned short* gA1 = xbf + (size_t)t1 * DMODEL + pA1 * 8;
    const unsigned short* gB0 = w1t + ((size_t)e * DFF + n0 + rA0) * DMODEL + pA0 * 8;
    const unsigned short* gB1 = w1t + ((size_t)e * DFF + n0 + rA1) * DMODEL + pA1 * 8;
    unsigned short* lA0 = As + (size_t)(wave * 64) * 8;
    unsigned short* lA1 = As + (size_t)(256 + wave * 64) * 8;
    unsigned short* lB0 = Bs + (size_t)(wave * 64) * 8;
    unsigned short* lB1 = Bs + (size_t)(256 + wave * 64) * 8;

    const int wm = (wave >> 1) * 64, wn = (wave & 1) * 64;
    const int mrow = lane & 15, kq = (lane >> 4) * 8;
    facc acc[4][4] = {};

    for (int kb = 0; kb < DMODEL; kb += 32) {
        gl2lds16(gA0 + kb, lA0);
        gl2lds16(gA1 + kb, lA1);
        gl2lds16(gB0 + kb, lB0);
        gl2lds16(gB1 + kb, lB1);
        __syncthreads();
        vs8 af[4], bfr[4];
        #pragma unroll
        for (int i = 0; i < 4; ++i)
            af[i] = *(const vs8*)(As + (wm + i * 16 + mrow) * 32 + kq);
        #pragma unroll
        for (int i = 0; i < 4; ++i)
            bfr[i] = *(const vs8*)(Bs + (wn + i * 16 + mrow) * 32 + kq);
        #pragma unroll
        for (int i = 0; i < 4; ++i)
            #pragma unroll
            for (int j = 0; j < 4; ++j)
                acc[i][j] = __builtin_amdgcn_mfma_f32_16x16x32_bf16(af[i], bfr[j], acc[i][j], 0, 0, 0);
        __syncthreads();
    }

    const int quad = lane >> 4, col = lane & 15;
    #pragma unroll
    for (int i = 0; i < 4; ++i) {
        #pragma unroll
        for (int r = 0; r < 4; ++r) {
            const int mloc = wm + i * 16 + quad * 4 + r;
            if (m0 + mloc < cnt) {
                unsigned short* hrow = h + (size_t)(rb + m0 + mloc) * DFF + n0;
                #pragma unroll
                for (int j = 0; j < 4; ++j) {
                    float v = acc[i][j][r];
                    v = 0.5f * v * (1.0f + erff(v * 0.70710678118654752f));
                    hrow[wn + j * 16 + col] = f2bf(v);
                }
            }
        }
    }
}

// ---------------- pass B: out += w * (H @ W2[e]), grouped 128x128, atomic scatter ----------------
__global__ __launch_bounds__(256) void k_ffn2(
    const unsigned short* __restrict__ h, const unsigned short* __restrict__ w2t,
    const int* __restrict__ counts, const int* __restrict__ bases,
    const int* __restrict__ row_token, const float* __restrict__ row_weight,
    float* __restrict__ out) {
    __shared__ unsigned short As[128 * 32];
    __shared__ unsigned short Bs[128 * 32];
    __shared__ int   tokl[128];
    __shared__ float wl[128];
    const int e = blockIdx.z;
    const int cnt = counts[e];
    const int m0 = blockIdx.y * 128;
    if (m0 >= cnt) return;
    const int n0 = blockIdx.x * 128;
    const int rb = bases[e];
    const int tid = threadIdx.x;
    const int wave = tid >> 6, lane = tid & 63;

    if (tid < 128) {
        int gr = m0 + tid;
        bool vv = gr < cnt;
        tokl[tid] = vv ? row_token[rb + gr] : 0;
        wl[tid]   = vv ? row_weight[rb + gr] : 0.0f;
    }

    const int rA0 = tid >> 2,         pA0 = tid & 3;
    const int rA1 = (256 + tid) >> 2, pA1 = tid & 3;
    const unsigned short* gA0 = h + (size_t)(rb + imin(m0 + rA0, cnt - 1)) * DFF + pA0 * 8;
    const unsigned short* gA1 = h + (size_t)(rb + imin(m0 + rA1, cnt - 1)) * DFF + pA1 * 8;
    const unsigned short* gB0 = w2t + ((size_t)e * DMODEL + n0 + rA0) * DFF + pA0 * 8;
    const unsigned short* gB1 = w2t + ((size_t)e * DMODEL + n0 + rA1) * DFF + pA1 * 8;
    unsigned short* lA0 = As + (size_t)(wave * 64) * 8;
    unsigned short* lA1 = As + (size_t)(256 + wave * 64) * 8;
    unsigned short* lB0 = Bs + (size_t)(wave * 64) * 8;
    unsigned short* lB1 = Bs + (size_t)(256 + wave * 64) * 8;

    const int wm = (wave >> 1) * 64, wn = (wave & 1) * 64;
    const int mrow = lane & 15, kq = (lane >> 4) * 8;
    facc acc[4][4] = {};

    for (int kb = 0; kb < DFF; kb += 32) {
        gl2lds16(gA0 + kb, lA0);
        gl2lds16(gA1 + kb, lA1);
        gl2lds16(gB0 + kb, lB0);
        gl2lds16(gB1 + kb, lB1);
        __syncthreads();
        vs8 af[4], bfr[4];
        #pragma unroll
        for (int i = 0; i < 4; ++i)
            af[i] = *(const vs8*)(As + (wm + i * 16 + mrow) * 32 + kq);
        #pragma unroll
        for (int i = 0; i < 4; ++i)
            bfr[i] = *(const vs8*)(Bs + (wn + i * 16 + mrow) * 32 + kq);
        #pragma unroll
        for (int i = 0; i < 4; ++i)
            #pragma unroll
            for (int j = 0; j < 4; ++j)
                acc[i][j] = __builtin_amdgcn_mfma_f32_16x16x32_bf16(af[i], bfr[j], acc[i][j], 0, 0, 0);
        __syncthreads();
    }

    const int quad = lane >> 4, col = lane & 15;
    #pragma unroll
    for (int i = 0; i < 4; ++i) {
        #pragma unroll
        for (int r = 0; r < 4; ++r) {
            const int mloc = wm + i * 16 + quad * 4 + r;
            if (m0 + mloc < cnt) {
                const float w = wl[mloc];
                float* orow = out + (size_t)tokl[mloc] * DMODEL + n0;
                #pragma unroll
                for (int j = 0; j < 4; ++j)
                    atomicAdd(&orow[wn + j * 16 + col], acc[i][j][r] * w);
            }
        }
    }
}

extern "C" void kernel_launch(void* const* d_in, const int* in_sizes, int n_in,
                              void* d_out, int out_size, void* d_ws, size_t ws_size,
                              hipStream_t stream) {
    const float* x  = (const float*)d_in[0];
    const float* Wg = (const float*)d_in[1];
    const float* W1 = (const float*)d_in[2];
    const float* W2 = (const float*)d_in[3];
    float* out = (float*)d_out;

    char* ws = (char*)d_ws;
    int*   counts     = (int*)  (ws + 0);
    int*   cursors    = (int*)  (ws + 32);
    float* probsum    = (float*)(ws + 64);
    int*   bases      = (int*)  (ws + 96);
    int*   tk_e       = (int*)  (ws + 256);
    float* tk_w       = (float*)(ws + 256 + 65536);
    int*   row_token  = (int*)  (ws + 256 + 131072);
    float* row_weight = (float*)(ws + 256 + 196608);
    unsigned short* xbf = (unsigned short*)(ws + 262400);
    unsigned short* w1t = xbf + (size_t)TOKENS * DMODEL;
    unsigned short* w2t = w1t + (size_t)NEXP * DMODEL * DFF;
    unsigned short* hbuf = w2t + (size_t)NEXP * DMODEL * DFF;
    // total ws use: 262400 + 16MiB + 64MiB + 64MiB + 128MiB ~= 272.3 MiB

    hipMemsetAsync(d_out, 0, (size_t)out_size * sizeof(float), stream);
    hipMemsetAsync(ws, 0, 256, stream);

    k_convert_x<<<(TOKENS * DMODEL) / 1024, 256, 0, stream>>>(x, xbf);
    k_transpose_bf<<<dim3(DFF / 64, DMODEL / 64, NEXP), 256, 0, stream>>>(W1, w1t, DMODEL, DFF);
    k_transpose_bf<<<dim3(DMODEL / 64, DFF / 64, NEXP), 256, 0, stream>>>(W2, w2t, DFF, DMODEL);
    k_gate<<<TOKENS, 64, 0, stream>>>(x, Wg, counts, probsum, tk_e, tk_w);
    k_finalize<<<1, 64, 0, stream>>>(counts, probsum, bases, out + (out_size - 1));
    k_build<<<NROWS / 256, 256, 0, stream>>>(tk_e, tk_w, bases, cursors, row_token, row_weight);
    k_ffn1<<<dim3(DFF / 128, TOKENS / 128, NEXP), 256, 0, stream>>>(xbf, w1t, counts, bases, row_token, hbuf);
    k_ffn2<<<dim3(DMODEL / 128, TOKENS / 128, NEXP), 256, 0, stream>>>(hbuf, w2t, counts, bases, row_token, row_weight, out);
}

// Round 2
// 835.407 us; speedup vs baseline: 2.0701x; 2.0701x over previous
//
#include <hip/hip_runtime.h>
#include <math.h>
#include <stdint.h>

#define TOKENS 8192
#define DMODEL 1024
#define DFF    4096
#define NEXP   8
#define NROWS  (TOKENS * 2)

typedef float          vf4 __attribute__((ext_vector_type(4)));
typedef unsigned short vu4 __attribute__((ext_vector_type(4)));
typedef short          vs8 __attribute__((ext_vector_type(8)));
typedef float          facc __attribute__((ext_vector_type(4)));

__device__ __forceinline__ unsigned short f2bf(float f) {
    union { float f; unsigned u; } v; v.f = f;
    return (unsigned short)((v.u + 0x7FFFu + ((v.u >> 16) & 1u)) >> 16);
}
__device__ __forceinline__ int imin(int a, int b) { return a < b ? a : b; }

__device__ __forceinline__ void gl2lds16(const void* g, void* l) {
    __builtin_amdgcn_global_load_lds(
        (const __attribute__((address_space(1))) unsigned int*)g,
        (__attribute__((address_space(3))) unsigned int*)l, 16, 0, 0);
}

// ---------------- x fp32 -> bf16 ----------------
__global__ void k_convert_x(const float* __restrict__ x, unsigned short* __restrict__ xbf) {
    int i = blockIdx.x * 256 + threadIdx.x;   // one float4 per thread
    vf4 v = ((const vf4*)x)[i];
    vu4 o;
    o[0] = f2bf(v[0]); o[1] = f2bf(v[1]); o[2] = f2bf(v[2]); o[3] = f2bf(v[3]);
    ((vu4*)xbf)[i] = o;
}

// ---------------- transpose + bf16 convert: src[e][R][C] f32 -> dst[e][C][R] bf16 ----------------
__global__ void k_transpose_bf(const float* __restrict__ src, unsigned short* __restrict__ dst,
                               int R, int C) {
    __shared__ float tile[64][65];
    const int e = blockIdx.z;
    const float* s = src + (size_t)e * R * C;
    unsigned short* d = dst + (size_t)e * R * C;
    const int r0 = blockIdx.y * 64, c0 = blockIdx.x * 64;
    const int tr = threadIdx.x >> 4;          // 0..15
    const int tc = (threadIdx.x & 15) * 4;    // 0..60
    #pragma unroll
    for (int p = 0; p < 4; ++p) {
        int r = p * 16 + tr;
        vf4 v = *(const vf4*)(s + (size_t)(r0 + r) * C + c0 + tc);
        tile[r][tc + 0] = v[0]; tile[r][tc + 1] = v[1];
        tile[r][tc + 2] = v[2]; tile[r][tc + 3] = v[3];
    }
    __syncthreads();
    #pragma unroll
    for (int p = 0; p < 4; ++p) {
        int cc = p * 16 + tr;                 // transposed row index (c-dim)
        vu4 o;
        o[0] = f2bf(tile[tc + 0][cc]); o[1] = f2bf(tile[tc + 1][cc]);
        o[2] = f2bf(tile[tc + 2][cc]); o[3] = f2bf(tile[tc + 3][cc]);
        *(vu4*)(d + (size_t)(c0 + cc) * R + r0 + tc) = o;
    }
}

// ---------------- gate: logits -> softmax -> top2; NO global atomics ----------------
__global__ void k_gate(const float* __restrict__ x, const float* __restrict__ Wg,
                       float* __restrict__ probs,
                       int* __restrict__ tk_e, float* __restrict__ tk_w) {
    const int t = blockIdx.x;
    const int lane = threadIdx.x;             // 64 threads = 1 wave
    float acc[NEXP] = {0.f, 0.f, 0.f, 0.f, 0.f, 0.f, 0.f, 0.f};
    const float* xr = x + (size_t)t * DMODEL;
    #pragma unroll
    for (int i = 0; i < 16; ++i) {
        int dd = i * 64 + lane;
        float xv = xr[dd];
        const vf4* w = (const vf4*)(Wg + (size_t)dd * NEXP);
        vf4 a = w[0], b = w[1];
        acc[0] += xv * a[0]; acc[1] += xv * a[1]; acc[2] += xv * a[2]; acc[3] += xv * a[3];
        acc[4] += xv * b[0]; acc[5] += xv * b[1]; acc[6] += xv * b[2]; acc[7] += xv * b[3];
    }
    #pragma unroll
    for (int e = 0; e < NEXP; ++e) {
        float v = acc[e];
        for (int off = 32; off; off >>= 1) v += __shfl_xor(v, off, 64);
        acc[e] = v;
    }
    if (lane == 0) {
        float mx = acc[0];
        #pragma unroll
        for (int e = 1; e < NEXP; ++e) mx = fmaxf(mx, acc[e]);
        float p[NEXP], s = 0.f;
        #pragma unroll
        for (int e = 0; e < NEXP; ++e) { p[e] = expf(acc[e] - mx); s += p[e]; }
        float inv = 1.f / s;
        #pragma unroll
        for (int e = 0; e < NEXP; ++e) p[e] *= inv;
        vf4 p0 = {p[0], p[1], p[2], p[3]}, p1 = {p[4], p[5], p[6], p[7]};
        ((vf4*)(probs + (size_t)t * NEXP))[0] = p0;
        ((vf4*)(probs + (size_t)t * NEXP))[1] = p1;
        int i0 = 0; float b0 = p[0];
        #pragma unroll
        for (int e = 1; e < NEXP; ++e) if (p[e] > b0) { b0 = p[e]; i0 = e; }
        int i1 = -1; float b1 = -1.f;
        #pragma unroll
        for (int e = 0; e < NEXP; ++e) if (e != i0 && p[e] > b1) { b1 = p[e]; i1 = e; }
        float sn = 1.f / (b0 + b1 + 1e-8f);
        tk_e[t * 2 + 0] = i0; tk_w[t * 2 + 0] = b0 * sn;
        tk_e[t * 2 + 1] = i1; tk_w[t * 2 + 1] = b1 * sn;
    }
}

// ---------------- reduce probs -> probsum, tk_e -> counts (8 atomics/block) ----------------
__global__ void k_reduce(const float* __restrict__ probs, const int* __restrict__ tk_e,
                         float* __restrict__ probsum, int* __restrict__ counts) {
    __shared__ float psum_l[4][NEXP];
    __shared__ int hist_l[NEXP];
    const int tid = threadIdx.x;              // 256 threads, 32 blocks -> 8192 tokens
    const int wave = tid >> 6, lane = tid & 63;
    const int t = blockIdx.x * 256 + tid;
    if (tid < NEXP) hist_l[tid] = 0;
    vf4 p0 = ((const vf4*)(probs + (size_t)t * NEXP))[0];
    vf4 p1 = ((const vf4*)(probs + (size_t)t * NEXP))[1];
    float p[NEXP] = {p0[0], p0[1], p0[2], p0[3], p1[0], p1[1], p1[2], p1[3]};
    #pragma unroll
    for (int e = 0; e < NEXP; ++e) {
        float v = p[e];
        for (int off = 32; off; off >>= 1) v += __shfl_xor(v, off, 64);
        p[e] = v;
    }
    if (lane == 0) {
        #pragma unroll
        for (int e = 0; e < NEXP; ++e) psum_l[wave][e] = p[e];
    }
    __syncthreads();
    atomicAdd(&hist_l[tk_e[t * 2 + 0]], 1);
    atomicAdd(&hist_l[tk_e[t * 2 + 1]], 1);
    __syncthreads();
    if (tid < NEXP) {
        float s = psum_l[0][tid] + psum_l[1][tid] + psum_l[2][tid] + psum_l[3][tid];
        atomicAdd(&probsum[tid], s);
        atomicAdd(&counts[tid], hist_l[tid]);
    }
}

// ---------------- prefix bases + load-balance loss ----------------
__global__ void k_finalize(const int* __restrict__ counts, const float* __restrict__ probsum,
                           int* __restrict__ bases, float* __restrict__ out_loss) {
    if (threadIdx.x == 0) {
        int b = 0; float loss = 0.f;
        for (int e = 0; e < NEXP; ++e) {
            bases[e] = b; b += counts[e];
            loss += (probsum[e] / (float)TOKENS) * ((float)counts[e] / (float)NROWS);
        }
        out_loss[0] = (float)NEXP * loss;
    }
}

// ---------------- compact (token,slot) -> per-expert row lists; 8 atomics/block ----------------
__global__ void k_build(const int* __restrict__ tk_e, const float* __restrict__ tk_w,
                        const int* __restrict__ bases, int* __restrict__ cursors,
                        int* __restrict__ row_token, float* __restrict__ row_weight) {
    __shared__ int hist_l[NEXP];
    __shared__ int base_l[NEXP];
    const int tid = threadIdx.x;              // 64 blocks x 256 = 16384 entries
    const int i = blockIdx.x * 256 + tid;
    if (tid < NEXP) hist_l[tid] = 0;
    __syncthreads();
    const int e = tk_e[i];
    const int rank = atomicAdd(&hist_l[e], 1);   // within-block rank for expert e
    __syncthreads();
    if (tid < NEXP) base_l[tid] = atomicAdd(&cursors[tid], hist_l[tid]);
    __syncthreads();
    const int row = bases[e] + base_l[e] + rank;
    row_token[row] = i >> 1;
    row_weight[row] = tk_w[i];
}

// ---------------- pass A: H = gelu(X_gathered @ W1[e]), grouped 128x128 ----------------
__global__ __launch_bounds__(256) void k_ffn1(
    const unsigned short* __restrict__ xbf, const unsigned short* __restrict__ w1t,
    const int* __restrict__ counts, const int* __restrict__ bases,
    const int* __restrict__ row_token, unsigned short* __restrict__ h) {
    __shared__ unsigned short As[128 * 32];
    __shared__ unsigned short Bs[128 * 32];
    const int e = blockIdx.z;
    const int cnt = counts[e];
    const int m0 = blockIdx.y * 128;
    if (m0 >= cnt) return;
    const int n0 = blockIdx.x * 128;
    const int rb = bases[e];
    const int tid = threadIdx.x;
    const int wave = tid >> 6, lane = tid & 63;

    // staging: 512 16B-chunks per operand tile; slot s -> row s>>2, part s&3
    const int rA0 = tid >> 2,        pA0 = tid & 3;
    const int rA1 = (256 + tid) >> 2, pA1 = tid & 3;   // (256+tid)&3 == tid&3
    const int t0 = row_token[rb + imin(m0 + rA0, cnt - 1)];
    const int t1 = row_token[rb + imin(m0 + rA1, cnt - 1)];
    const unsigned short* gA0 = xbf + (size_t)t0 * DMODEL + pA0 * 8;
    const unsigned short* gA1 = xbf + (size_t)t1 * DMODEL + pA1 * 8;
    const unsigned short* gB0 = w1t + ((size_t)e * DFF + n0 + rA0) * DMODEL + pA0 * 8;
    const unsigned short* gB1 = w1t + ((size_t)e * DFF + n0 + rA1) * DMODEL + pA1 * 8;
    unsigned short* lA0 = As + (size_t)(wave * 64) * 8;
    unsigned short* lA1 = As + (size_t)(256 + wave * 64) * 8;
    unsigned short* lB0 = Bs + (size_t)(wave * 64) * 8;
    unsigned short* lB1 = Bs + (size_t)(256 + wave * 64) * 8;

    const int wm = (wave >> 1) * 64, wn = (wave & 1) * 64;
    const int mrow = lane & 15, kq = (lane >> 4) * 8;
    facc acc[4][4] = {};

    for (int kb = 0; kb < DMODEL; kb += 32) {
        gl2lds16(gA0 + kb, lA0);
        gl2lds16(gA1 + kb, lA1);
        gl2lds16(gB0 + kb, lB0);
        gl2lds16(gB1 + kb, lB1);
        __syncthreads();
        vs8 af[4], bfr[4];
        #pragma unroll
        for (int i = 0; i < 4; ++i)
            af[i] = *(const vs8*)(As + (wm + i * 16 + mrow) * 32 + kq);
        #pragma unroll
        for (int i = 0; i < 4; ++i)
            bfr[i] = *(const vs8*)(Bs + (wn + i * 16 + mrow) * 32 + kq);
        #pragma unroll
        for (int i = 0; i < 4; ++i)
            #pragma unroll
            for (int j = 0; j < 4; ++j)
                acc[i][j] = __builtin_amdgcn_mfma_f32_16x16x32_bf16(af[i], bfr[j], acc[i][j], 0, 0, 0);
        __syncthreads();
    }

    const int quad = lane >> 4, col = lane & 15;
    #pragma unroll
    for (int i = 0; i < 4; ++i) {
        #pragma unroll
        for (int r = 0; r < 4; ++r) {
            const int mloc = wm + i * 16 + quad * 4 + r;
            if (m0 + mloc < cnt) {
                unsigned short* hrow = h + (size_t)(rb + m0 + mloc) * DFF + n0;
                #pragma unroll
                for (int j = 0; j < 4; ++j) {
                    float v = acc[i][j][r];
                    v = 0.5f * v * (1.0f + erff(v * 0.70710678118654752f));
                    hrow[wn + j * 16 + col] = f2bf(v);
                }
            }
        }
    }
}

// ---------------- pass B: out += w * (H @ W2[e]), grouped 128x128, atomic scatter ----------------
__global__ __launch_bounds__(256) void k_ffn2(
    const unsigned short* __restrict__ h, const unsigned short* __restrict__ w2t,
    const int* __restrict__ counts, const int* __restrict__ bases,
    const int* __restrict__ row_token, const float* __restrict__ row_weight,
    float* __restrict__ out) {
    __shared__ unsigned short As[128 * 32];
    __shared__ unsigned short Bs[128 * 32];
    __shared__ int   tokl[128];
    __shared__ float wl[128];
    const int e = blockIdx.z;
    const int cnt = counts[e];
    const int m0 = blockIdx.y * 128;
    if (m0 >= cnt) return;
    const int n0 = blockIdx.x * 128;
    const int rb = bases[e];
    const int tid = threadIdx.x;
    const int wave = tid >> 6, lane = tid & 63;

    if (tid < 128) {
        int gr = m0 + tid;
        bool vv = gr < cnt;
        tokl[tid] = vv ? row_token[rb + gr] : 0;
        wl[tid]   = vv ? row_weight[rb + gr] : 0.0f;
    }

    const int rA0 = tid >> 2,         pA0 = tid & 3;
    const int rA1 = (256 + tid) >> 2, pA1 = tid & 3;
    const unsigned short* gA0 = h + (size_t)(rb + imin(m0 + rA0, cnt - 1)) * DFF + pA0 * 8;
    const unsigned short* gA1 = h + (size_t)(rb + imin(m0 + rA1, cnt - 1)) * DFF + pA1 * 8;
    const unsigned short* gB0 = w2t + ((size_t)e * DMODEL + n0 + rA0) * DFF + pA0 * 8;
    const unsigned short* gB1 = w2t + ((size_t)e * DMODEL + n0 + rA1) * DFF + pA1 * 8;
    unsigned short* lA0 = As + (size_t)(wave * 64) * 8;
    unsigned short* lA1 = As + (size_t)(256 + wave * 64) * 8;
    unsigned short* lB0 = Bs + (size_t)(wave * 64) * 8;
    unsigned short* lB1 = Bs + (size_t)(256 + wave * 64) * 8;

    const int wm = (wave >> 1) * 64, wn = (wave & 1) * 64;
    const int mrow = lane & 15, kq = (lane >> 4) * 8;
    facc acc[4][4] = {};

    for (int kb = 0; kb < DFF; kb += 32) {
        gl2lds16(gA0 + kb, lA0);
        gl2lds16(gA1 + kb, lA1);
        gl2lds16(gB0 + kb, lB0);
        gl2lds16(gB1 + kb, lB1);
        __syncthreads();
        vs8 af[4], bfr[4];
        #pragma unroll
        for (int i = 0; i < 4; ++i)
            af[i] = *(const vs8*)(As + (wm + i * 16 + mrow) * 32 + kq);
        #pragma unroll
        for (int i = 0; i < 4; ++i)
            bfr[i] = *(const vs8*)(Bs + (wn + i * 16 + mrow) * 32 + kq);
        #pragma unroll
        for (int i = 0; i < 4; ++i)
            #pragma unroll
            for (int j = 0; j < 4; ++j)
                acc[i][j] = __builtin_amdgcn_mfma_f32_16x16x32_bf16(af[i], bfr[j], acc[i][j], 0, 0, 0);
        __syncthreads();
    }

    const int quad = lane >> 4, col = lane & 15;
    #pragma unroll
    for (int i = 0; i < 4; ++i) {
        #pragma unroll
        for (int r = 0; r < 4; ++r) {
            const int mloc = wm + i * 16 + quad * 4 + r;
            if (m0 + mloc < cnt) {
                const float w = wl[mloc];
                float* orow = out + (size_t)tokl[mloc] * DMODEL + n0;
                #pragma unroll
                for (int j = 0; j < 4; ++j)
                    atomicAdd(&orow[wn + j * 16 + col], acc[i][j][r] * w);
            }
        }
    }
}

extern "C" void kernel_launch(void* const* d_in, const int* in_sizes, int n_in,
                              void* d_out, int out_size, void* d_ws, size_t ws_size,
                              hipStream_t stream) {
    const float* x  = (const float*)d_in[0];
    const float* Wg = (const float*)d_in[1];
    const float* W1 = (const float*)d_in[2];
    const float* W2 = (const float*)d_in[3];
    float* out = (float*)d_out;

    char* ws = (char*)d_ws;
    int*   counts     = (int*)  (ws + 0);
    int*   cursors    = (int*)  (ws + 32);
    float* probsum    = (float*)(ws + 64);
    int*   bases      = (int*)  (ws + 96);
    int*   tk_e       = (int*)  (ws + 256);
    float* tk_w       = (float*)(ws + 256 + 65536);
    int*   row_token  = (int*)  (ws + 256 + 131072);
    float* row_weight = (float*)(ws + 256 + 196608);
    float* probs      = (float*)(ws + 262400);            // 8192*8*4 = 256 KiB
    unsigned short* xbf = (unsigned short*)(ws + 524544);
    unsigned short* w1t = xbf + (size_t)TOKENS * DMODEL;
    unsigned short* w2t = w1t + (size_t)NEXP * DMODEL * DFF;
    unsigned short* hbuf = w2t + (size_t)NEXP * DMODEL * DFF;
    // total ws use: ~0.5 MiB + 16MiB + 64MiB + 64MiB + 128MiB ~= 272.5 MiB

    hipMemsetAsync(d_out, 0, (size_t)out_size * sizeof(float), stream);
    hipMemsetAsync(ws, 0, 256, stream);

    k_convert_x<<<(TOKENS * DMODEL) / 1024, 256, 0, stream>>>(x, xbf);
    k_transpose_bf<<<dim3(DFF / 64, DMODEL / 64, NEXP), 256, 0, stream>>>(W1, w1t, DMODEL, DFF);
    k_transpose_bf<<<dim3(DMODEL / 64, DFF / 64, NEXP), 256, 0, stream>>>(W2, w2t, DFF, DMODEL);
    k_gate<<<TOKENS, 64, 0, stream>>>(x, Wg, probs, tk_e, tk_w);
    k_reduce<<<TOKENS / 256, 256, 0, stream>>>(probs, tk_e, probsum, counts);
    k_finalize<<<1, 64, 0, stream>>>(counts, probsum, bases, out + (out_size - 1));
    k_build<<<NROWS / 256, 256, 0, stream>>>(tk_e, tk_w, bases, cursors, row_token, row_weight);
    k_ffn1<<<dim3(DFF / 128, TOKENS / 128, NEXP), 256, 0, stream>>>(xbf, w1t, counts, bases, row_token, hbuf);
    k_ffn2<<<dim3(DMODEL / 128, TOKENS / 128, NEXP), 256, 0, stream>>>(hbuf, w2t, counts, bases, row_token, row_weight, out);
}